// Round 5
// baseline (340.796 us; speedup 1.0000x reference)
//
#include <hip/hip_runtime.h>
#include <hip/hip_bf16.h>
#include <stdint.h>

typedef short s8v __attribute__((ext_vector_type(8)));
typedef float f4v __attribute__((ext_vector_type(4)));

__device__ __align__(16) float g_zeros[4] = {0.f, 0.f, 0.f, 0.f};

__device__ __forceinline__ void async_copy16(const void* gsrc, void* lds_dst) {
  __builtin_amdgcn_global_load_lds(
      (const __attribute__((address_space(1))) uint32_t*)(uintptr_t)gsrc,
      (__attribute__((address_space(3))) uint32_t*)(uint32_t)(uintptr_t)lds_dst,
      16, 0, 0);
}

#define WAITVM(N) asm volatile("s_waitcnt vmcnt(" #N ")" ::: "memory")
__device__ __forceinline__ void block_barrier() {
  asm volatile("" ::: "memory");
  __builtin_amdgcn_s_barrier();
  asm volatile("" ::: "memory");
}

// ---------------- W pack: [co][ci][kh][kw] fp32 -> [kh*5+kw][co][ci] bf16 ----------------
// One block per co; coalesced reads and writes. Block 0 also zeroes gstats.
__global__ __launch_bounds__(256) void wpack_kernel(const float* __restrict__ W,
                                                    __hip_bfloat16* __restrict__ Wr,
                                                    float* __restrict__ gstats) {
  __shared__ __hip_bfloat16 t[256 * 26];  // [ci][pos], pad to 26
  const int co = blockIdx.x;
  const int tid = threadIdx.x;
  if (co == 0) gstats[tid] = 0.f;  // 256 floats: sum[128], ssq[128]
  const float* src = W + co * 6400;
  for (int i = tid; i < 6400; i += 256) {
    int ci = i / 25;
    int pos = i - ci * 25;
    t[ci * 26 + pos] = __float2bfloat16(src[i]);
  }
  __syncthreads();
  for (int pos = 0; pos < 25; ++pos)
    Wr[pos * 32768 + co * 256 + tid] = t[tid * 26 + pos];
}

// ---------------- Upsample: x NCHW fp32 (8,256,64,64) -> up NHWC bf16 (8,128,128,256) ----------------
// grid: b(8) x cb(4,64ch) x ohb(8,16 rows) x owb(2,64 cols) = 512 blocks
__global__ __launch_bounds__(256, 2) void upsample_kernel(const float* __restrict__ x,
                                                          __hip_bfloat16* __restrict__ up) {
  __shared__ __hip_bfloat16 lx[10 * 48 * 66];  // [ih 10][iw 48][c 64 + 2 pad]
  const int tid = threadIdx.x;
  const int bx = blockIdx.x;
  const int owb = bx & 1;
  const int ohb = (bx >> 1) & 7;
  const int cb = (bx >> 4) & 3;
  const int b = bx >> 6;
  const int oh0 = ohb * 16, ow0 = owb * 64, c0 = cb * 64;
  const int ih0 = (oh0 >> 1) - 1;                    // may be -1
  const int iw_lo = (ow0 >> 1) - 1;
  const int aligned = (iw_lo < 0 ? 0 : iw_lo) & ~15; // 0 or 16

  for (int i = tid; i < 64 * 10 * 12; i += 256) {    // float4 loads along iw
    int c = i / 120;
    int rem = i - c * 120;
    int r = rem / 12;
    int w4 = (rem - r * 12) * 4;
    int gr = ih0 + r;
    gr = gr < 0 ? 0 : (gr > 63 ? 63 : gr);
    const float4 v = *(const float4*)&x[(((b * 256 + c0 + c) * 64) + gr) * 64 + aligned + w4];
    int base = (r * 48 + w4) * 66 + c;
    lx[base]       = __float2bfloat16(v.x);
    lx[base + 66]  = __float2bfloat16(v.y);
    lx[base + 132] = __float2bfloat16(v.z);
    lx[base + 198] = __float2bfloat16(v.w);
  }
  __syncthreads();

  // 2 channels per thread: b32 LDS reads, packed bf16x2 global stores
  const int c2 = (tid & 31) * 2;
  const int owq = tid >> 5;  // 0..7
  uint32_t* upu = (uint32_t*)up;
  for (int it = 0; it < 128; ++it) {
    int oh_l = it >> 3;
    int ow_l = (it & 7) * 8 + owq;
    int oh = oh0 + oh_l, ow = ow0 + ow_l;
    int ihA = (oh >> 1) - ((oh & 1) ^ 1);            // first tap row
    float wh = (oh & 1) ? 0.75f : 0.25f;             // its weight
    int iwA = (ow >> 1) - ((ow & 1) ^ 1);
    float wwt = (ow & 1) ? 0.75f : 0.25f;
    int r0 = ihA - ih0;                               // slot content is pre-clamped
    int w0 = (iwA < 0 ? 0 : iwA) - aligned;
    int w1t = iwA + 1; w1t = w1t > 63 ? 63 : w1t;
    int w1 = w1t - aligned;
    uint32_t t00 = *(const uint32_t*)&lx[(r0 * 48 + w0) * 66 + c2];
    uint32_t t01 = *(const uint32_t*)&lx[(r0 * 48 + w1) * 66 + c2];
    uint32_t t10 = *(const uint32_t*)&lx[((r0 + 1) * 48 + w0) * 66 + c2];
    uint32_t t11 = *(const uint32_t*)&lx[((r0 + 1) * 48 + w1) * 66 + c2];
    float wlo = wh * wwt, wlo1 = wh * (1.f - wwt);
    float whi = (1.f - wh) * wwt, whi1 = (1.f - wh) * (1.f - wwt);
    float vlo = wlo * __uint_as_float(t00 << 16) + wlo1 * __uint_as_float(t01 << 16) +
                whi * __uint_as_float(t10 << 16) + whi1 * __uint_as_float(t11 << 16);
    float vhi = wlo * __uint_as_float(t00 & 0xffff0000u) + wlo1 * __uint_as_float(t01 & 0xffff0000u) +
                whi * __uint_as_float(t10 & 0xffff0000u) + whi1 * __uint_as_float(t11 & 0xffff0000u);
    __hip_bfloat16 h0 = __float2bfloat16(vlo);
    __hip_bfloat16 h1 = __float2bfloat16(vhi);
    uint32_t pk = (uint32_t)(*(unsigned short*)&h0) | ((uint32_t)(*(unsigned short*)&h1) << 16);
    upu[((((size_t)(b * 128 + oh) * 128) + ow) * 256 + c0 + c2) >> 1] = pk;
  }
}

// ---------------- Conv: implicit GEMM, M=256 (4 rows x 64 ow) x N=128 couts, MFMA bf16 ----------------
// grid: 512 blocks (2 per CU) = b(8) x ohg(32) x owh(2), 512 threads (8 waves: 4 rows x 2 cout-halves,
// 64x64 wave tiles). 78 KB LDS + <=128 reg/wave (launch_bounds 512,4) -> 2 blocks/CU.
// Theory: per-block barriers convoy the 8 waves (read-burst then MFMA-burst, zero pipe overlap at
// 1 block/CU). Two INDEPENDENT blocks/CU sit at uncorrelated phases -> block A's LDS burst runs
// under block B's MFMA burst. Sync kept from r3/r4: counted vmcnt (never drain mid-loop).
// lA: 5-slot circular row window [72 iw+halo][64 ch] XOR-swizzled; OOB iw staged from g_zeros.
// lB: double-buffered [128 cout][64 ch] (stage->bnext, read bcur; WAR barrier after compute).
#define ASLOT 4608  // shorts per lA slot (72 rows * 64 ch)
__global__ __launch_bounds__(512, 4) void conv_kernel(const __hip_bfloat16* __restrict__ up,
                                                      const __hip_bfloat16* __restrict__ Wr,
                                                      float* __restrict__ out,
                                                      float* __restrict__ gstats) {
  __shared__ __align__(16) unsigned short lA[5 * ASLOT];     // 46080 B
  __shared__ __align__(16) unsigned short lB[2][128 * 64];   // 32768 B
  __shared__ float lsum[128], lssq[128];                     //  1024 B -> 79872 total

  const int tid = threadIdx.x;
  const int lane = tid & 63;
  const int wave = tid >> 6;
  const int wm = wave >> 1;   // output row within 4-row group
  const int wn = wave & 1;    // cout half
  const int lane15 = lane & 15;
  const int quad = lane >> 4;
  const int wb = wave << 6;   // wave chunk base

  const int bid = blockIdx.x;
  const int orig = ((bid & 7) << 6) | (bid >> 3);  // XCD-chunked: each XCD owns one batch image
  const int b = orig >> 6;
  const int oh0 = ((orig >> 1) & 31) << 2;
  const int ow0 = (orig & 1) << 6;

  const f4v zero4 = {0.f, 0.f, 0.f, 0.f};
  if (tid < 128) { lsum[tid] = 0.f; lssq[tid] = 0.f; }

  auto stageA = [&](int slot, const __hip_bfloat16* uprow) {  // 72 rows (iw ow0-4..ow0+67)
    int idx = wb + lane;
    int r = idx >> 3, pc = idx & 7;
    int cq = pc ^ (r & 7);
    int iw = ow0 - 4 + r;
    const void* src = ((unsigned)iw < 128u) ? (const void*)(uprow + iw * 256 + cq * 8)
                                            : (const void*)g_zeros;
    async_copy16(src, (void*)&lA[(slot * 576 + wb) * 8]);
    if (wave == 0) {  // tail chunks 512..575 (wave-uniform branch, full wave)
      int idx2 = 512 + lane;
      int r2 = idx2 >> 3, pc2 = idx2 & 7;
      int cq2 = pc2 ^ (r2 & 7);
      int iw2 = ow0 - 4 + r2;
      const void* src2 = ((unsigned)iw2 < 128u) ? (const void*)(uprow + iw2 * 256 + cq2 * 8)
                                                : (const void*)g_zeros;
      async_copy16(src2, (void*)&lA[(slot * 576 + 512) * 8]);
    }
  };
  auto stageB = [&](const __hip_bfloat16* wsrc, int bsel) {  // [128 cout][64 ch], 2 ops/wave
#pragma unroll
    for (int t = 0; t < 2; ++t) {
      int pl = t * 512 + wb + lane;
      int n = pl >> 3, pc = pl & 7;
      int cq = pc ^ (n & 7);
      async_copy16(wsrc + n * 256 + cq * 8, (void*)&lB[bsel][(t * 512 + wb) * 8]);
    }
  };

  f4v acc[4][4];
#pragma unroll
  for (int i = 0; i < 4; ++i)
#pragma unroll
    for (int j = 0; j < 4; ++j) acc[i][j] = zero4;

  // ---- prologue: prime lA rows oh0-2..oh0+1 (cb=0) + lB pos0 (cb=0) into buffer 0
  for (int rr = 0; rr < 4; ++rr) {
    int ih = oh0 + rr - 2;
    if ((unsigned)ih < 128u)
      stageA(ih % 5, up + (size_t)(b * 128 + ih) * 32768);
  }
  stageB(Wr, 0);
  __syncthreads();  // drains prologue DMA + makes lsum init visible (one-time)

  int buf = 0;
  for (int cb = 0; cb < 4; ++cb) {
    const int c0 = cb << 6;
    for (int kh = 0; kh < 5; ++kh) {
      const int ih = oh0 + wm + kh - 2;
      const bool rowok = (unsigned)ih < 128u;
      const int abase = rowok ? (ih % 5) * ASLOT : 0;
      for (int kw = 0; kw < 5; ++kw) {
        const int pos = kh * 5 + kw;
        // ---- stage phase ----
        if (cb != 0 && pos == 0) {  // cb boundary: re-prime window at new channels
          for (int rr = 0; rr < 4; ++rr) {  // issued FIRST so the counted wait drains them next round
            int ihn = oh0 + rr - 2;
            if ((unsigned)ihn < 128u)
              stageA(ihn % 5, up + (size_t)(b * 128 + ihn) * 32768 + c0);
          }
        }
        if (pos < 24)      stageB(Wr + (size_t)(pos + 1) * 32768 + c0, buf ^ 1);
        else if (cb < 3)   stageB(Wr + (c0 + 64), buf ^ 1);  // next cb, pos0
        const bool extraA = (kw == 2) && (kh < 4) && (oh0 + kh + 2 < 128);
        if (extraA)  // lA row for kh+1; target slot disjoint from current-round read slots
          stageA((oh0 + kh + 2) % 5, up + (size_t)(b * 128 + oh0 + kh + 2) * 32768 + c0);
        // ---- counted wait (this round's ops stay in flight; prior round's have landed) ----
        // N = min per-wave ops issued THIS round (wave0's extra stageA tail over-waits slightly).
        if (pos == 24 && cb == 3)      { WAITVM(0); }
        else if (cb != 0 && pos == 0)  { WAITVM(6); }   // 4x stageA + stageB
        else if (extraA)               { WAITVM(3); }   // stageB + stageA
        else                           { WAITVM(2); }   // stageB only
        block_barrier();
        // ---- compute (prioritized; cross-block arbitration favors MFMA-phase waves) ----
        if (rowok) {
          __builtin_amdgcn_s_setprio(1);
#pragma unroll
          for (int ks = 0; ks < 2; ++ks) {
            const int cq = ks * 4 + quad;
            s8v a[4], bb[4];
#pragma unroll
            for (int mt = 0; mt < 4; ++mt) {
              int r = mt * 16 + lane15 + kw + 2;  // +2: lA row r <-> iw = ow0-4+r
              a[mt] = *(const s8v*)&lA[abase + (r * 8 + (cq ^ (r & 7))) * 8];
            }
#pragma unroll
            for (int nt = 0; nt < 4; ++nt) {
              int n = (wn << 6) + nt * 16 + lane15;
              bb[nt] = *(const s8v*)&lB[buf][(n * 8 + (cq ^ (n & 7))) * 8];
            }
#pragma unroll
            for (int mt = 0; mt < 4; ++mt)
#pragma unroll
              for (int nt = 0; nt < 4; ++nt)
                acc[mt][nt] = __builtin_amdgcn_mfma_f32_16x16x32_bf16(a[mt], bb[nt], acc[mt][nt], 0, 0, 0);
          }
          __builtin_amdgcn_s_setprio(0);
        }
        block_barrier();  // WAR: next round's DMA may overwrite lB[buf^1] / lA slots
        buf ^= 1;
      }
    }
  }

  // ---- epilogue: direct stores from acc (D: cout=lane&15, ow=mt*16+quad*4+reg) + stats
  const int oh = oh0 + wm;
#pragma unroll
  for (int nt = 0; nt < 4; ++nt) {
    const int n = (wn << 6) + nt * 16 + lane15;
    float* oc = out + ((size_t)(b * 128 + n) * 128 + oh) * 128 + ow0;
    float s = 0.f, ss = 0.f;
#pragma unroll
    for (int mt = 0; mt < 4; ++mt) {
      f4v v = acc[mt][nt];
      *(f4v*)&oc[mt * 16 + (quad << 2)] = v;
      s += v.x + v.y + v.z + v.w;
      ss += v.x * v.x + v.y * v.y + v.z * v.z + v.w * v.w;
    }
    s += __shfl_xor(s, 16, 64); ss += __shfl_xor(ss, 16, 64);
    s += __shfl_xor(s, 32, 64); ss += __shfl_xor(ss, 32, 64);
    if (quad == 0) { atomicAdd(&lsum[n], s); atomicAdd(&lssq[n], ss); }
  }
  __syncthreads();
  if (tid < 128) {
    atomicAdd(&gstats[tid], lsum[tid]);
    atomicAdd(&gstats[128 + tid], lssq[tid]);
  }
}

// ---------------- Normalize + ReLU in-place, grid-stride ----------------
__global__ __launch_bounds__(256) void norm_kernel(float* __restrict__ out,
                                                   const float* __restrict__ gstats,
                                                   const float* __restrict__ gamma,
                                                   const float* __restrict__ beta) {
  for (int i = blockIdx.x * 256 + threadIdx.x; i < 4194304; i += 2048 * 256) {
    f4v v = ((f4v*)out)[i];
    int c = (i >> 12) & 127;
    float mean = gstats[c] * (1.f / 131072.f);
    float var = gstats[128 + c] * (1.f / 131072.f) - mean * mean;
    float sc = gamma[c] * rsqrtf(var + 1e-5f);
    float bi = beta[c] - mean * sc;
    v.x = fmaxf(fmaf(v.x, sc, bi), 0.f);
    v.y = fmaxf(fmaf(v.y, sc, bi), 0.f);
    v.z = fmaxf(fmaf(v.z, sc, bi), 0.f);
    v.w = fmaxf(fmaf(v.w, sc, bi), 0.f);
    ((f4v*)out)[i] = v;
  }
}

extern "C" void kernel_launch(void* const* d_in, const int* in_sizes, int n_in,
                              void* d_out, int out_size, void* d_ws, size_t ws_size,
                              hipStream_t stream) {
  (void)in_sizes; (void)n_in; (void)out_size; (void)ws_size;
  const float* x = (const float*)d_in[0];
  const float* W = (const float*)d_in[1];
  const float* gamma = (const float*)d_in[2];
  const float* beta = (const float*)d_in[3];
  float* out = (float*)d_out;
  char* ws = (char*)d_ws;
  __hip_bfloat16* up = (__hip_bfloat16*)ws;                       // 67,108,864 B
  __hip_bfloat16* Wr = (__hip_bfloat16*)(ws + 67108864);          // 1,638,400 B
  float* gstats = (float*)(ws + 67108864 + 1638400);              // sum[128], sumsq[128]

  wpack_kernel<<<128, 256, 0, stream>>>(W, Wr, gstats);           // also zeroes gstats
  upsample_kernel<<<512, 256, 0, stream>>>(x, up);
  conv_kernel<<<512, 512, 0, stream>>>(up, Wr, out, gstats);
  norm_kernel<<<2048, 256, 0, stream>>>(out, gstats, gamma, beta);
}

// Round 6
// 332.654 us; speedup vs baseline: 1.0245x; 1.0245x over previous
//
#include <hip/hip_runtime.h>
#include <hip/hip_bf16.h>
#include <stdint.h>

typedef short s8v __attribute__((ext_vector_type(8)));
typedef float f4v __attribute__((ext_vector_type(4)));

__device__ __forceinline__ void async_copy16(const void* gsrc, void* lds_dst) {
  __builtin_amdgcn_global_load_lds(
      (const __attribute__((address_space(1))) uint32_t*)(uintptr_t)gsrc,
      (__attribute__((address_space(3))) uint32_t*)(uint32_t)(uintptr_t)lds_dst,
      16, 0, 0);
}

#define WAITVM(N) asm volatile("s_waitcnt vmcnt(" #N ")" ::: "memory")
__device__ __forceinline__ void block_barrier() {
  asm volatile("" ::: "memory");
  __builtin_amdgcn_s_barrier();
  asm volatile("" ::: "memory");
}

// ---------------- W pack: [co][ci][kh][kw] fp32 -> [kh*5+kw][co][ci] bf16 ----------------
__global__ __launch_bounds__(256) void wpack_kernel(const float* __restrict__ W,
                                                    __hip_bfloat16* __restrict__ Wr,
                                                    float* __restrict__ gstats) {
  __shared__ __hip_bfloat16 t[256 * 26];  // [ci][pos], pad to 26
  const int co = blockIdx.x;
  const int tid = threadIdx.x;
  if (co == 0) gstats[tid] = 0.f;  // 256 floats: sum[128], ssq[128]
  const float* src = W + co * 6400;
  for (int i = tid; i < 6400; i += 256) {
    int ci = i / 25;
    int pos = i - ci * 25;
    t[ci * 26 + pos] = __float2bfloat16(src[i]);
  }
  __syncthreads();
  for (int pos = 0; pos < 25; ++pos)
    Wr[pos * 32768 + co * 256 + tid] = t[tid * 26 + pos];
}

// ---------------- Upsample: x NCHW fp32 (8,256,64,64) -> up NHWC bf16 (8,128,128,256) ----------------
__global__ __launch_bounds__(256, 2) void upsample_kernel(const float* __restrict__ x,
                                                          __hip_bfloat16* __restrict__ up) {
  __shared__ __hip_bfloat16 lx[10 * 48 * 66];  // [ih 10][iw 48][c 64 + 2 pad]
  const int tid = threadIdx.x;
  const int bx = blockIdx.x;
  const int owb = bx & 1;
  const int ohb = (bx >> 1) & 7;
  const int cb = (bx >> 4) & 3;
  const int b = bx >> 6;
  const int oh0 = ohb * 16, ow0 = owb * 64, c0 = cb * 64;
  const int ih0 = (oh0 >> 1) - 1;                    // may be -1
  const int iw_lo = (ow0 >> 1) - 1;
  const int aligned = (iw_lo < 0 ? 0 : iw_lo) & ~15; // 0 or 16

  for (int i = tid; i < 64 * 10 * 12; i += 256) {    // float4 loads along iw
    int c = i / 120;
    int rem = i - c * 120;
    int r = rem / 12;
    int w4 = (rem - r * 12) * 4;
    int gr = ih0 + r;
    gr = gr < 0 ? 0 : (gr > 63 ? 63 : gr);
    const float4 v = *(const float4*)&x[(((b * 256 + c0 + c) * 64) + gr) * 64 + aligned + w4];
    int base = (r * 48 + w4) * 66 + c;
    lx[base]       = __float2bfloat16(v.x);
    lx[base + 66]  = __float2bfloat16(v.y);
    lx[base + 132] = __float2bfloat16(v.z);
    lx[base + 198] = __float2bfloat16(v.w);
  }
  __syncthreads();

  const int c2 = (tid & 31) * 2;
  const int owq = tid >> 5;  // 0..7
  uint32_t* upu = (uint32_t*)up;
  for (int it = 0; it < 128; ++it) {
    int oh_l = it >> 3;
    int ow_l = (it & 7) * 8 + owq;
    int oh = oh0 + oh_l, ow = ow0 + ow_l;
    int ihA = (oh >> 1) - ((oh & 1) ^ 1);            // first tap row
    float wh = (oh & 1) ? 0.75f : 0.25f;             // its weight
    int iwA = (ow >> 1) - ((ow & 1) ^ 1);
    float wwt = (ow & 1) ? 0.75f : 0.25f;
    int r0 = ihA - ih0;                               // slot content is pre-clamped
    int w0 = (iwA < 0 ? 0 : iwA) - aligned;
    int w1t = iwA + 1; w1t = w1t > 63 ? 63 : w1t;
    int w1 = w1t - aligned;
    uint32_t t00 = *(const uint32_t*)&lx[(r0 * 48 + w0) * 66 + c2];
    uint32_t t01 = *(const uint32_t*)&lx[(r0 * 48 + w1) * 66 + c2];
    uint32_t t10 = *(const uint32_t*)&lx[((r0 + 1) * 48 + w0) * 66 + c2];
    uint32_t t11 = *(const uint32_t*)&lx[((r0 + 1) * 48 + w1) * 66 + c2];
    float wlo = wh * wwt, wlo1 = wh * (1.f - wwt);
    float whi = (1.f - wh) * wwt, whi1 = (1.f - wh) * (1.f - wwt);
    float vlo = wlo * __uint_as_float(t00 << 16) + wlo1 * __uint_as_float(t01 << 16) +
                whi * __uint_as_float(t10 << 16) + whi1 * __uint_as_float(t11 << 16);
    float vhi = wlo * __uint_as_float(t00 & 0xffff0000u) + wlo1 * __uint_as_float(t01 & 0xffff0000u) +
                whi * __uint_as_float(t10 & 0xffff0000u) + whi1 * __uint_as_float(t11 & 0xffff0000u);
    __hip_bfloat16 h0 = __float2bfloat16(vlo);
    __hip_bfloat16 h1 = __float2bfloat16(vhi);
    uint32_t pk = (uint32_t)(*(unsigned short*)&h0) | ((uint32_t)(*(unsigned short*)&h1) << 16);
    upu[((((size_t)(b * 128 + oh) * 128) + ow) * 256 + c0 + c2) >> 1] = pk;
  }
}

// ---------------- Conv: implicit GEMM, M=512 x N=128, MFMA bf16, register-pipelined ----------------
// grid: 256 blocks (1 per CU) = b(8) x ohg(32), 512 threads (8 waves: 4 rows x 2 cout-halves).
// Register fragment pipeline: enter each round (pos = cb*25+kh*5+kw) with ks0 fragments already
// in regs; {MFMA ks0 || ds_read ks1} then {MFMA ks1 || ds_read next-pos ks0}. MFMAs issue at
// barrier exit with zero lgkm dependency -> LDS pipe (1536 cy/round) hides under MFMA (2483 cy).
// lB QUAD-buffered (read t%4, stage (t+2)%4): 2-ahead staging + 1-round laggard skew + own
// prefetch (t+1) all disjoint mod 4 (mod 3 would collide t+2 == t-1).
// lA: 5-slot circular row window, stageA at kw==2; re-prime at cb boundary behind extra barrier.
// Counted vmcnt: wait at pos t leaves only this round's ops in flight -> t-1's stages landed,
// which is exactly what the t+1-prefetch (issued this round) reads.
#define ASLOT 8448  // shorts per lA slot (132 rows * 64 ch)

#define READ_A(S, KH, KW, KS)                                                 \
  { int ihr_ = oh0 + wm + (KH) - 2;                                           \
    if ((unsigned)ihr_ < 128u) {                                              \
      const unsigned short* ap_ = &lA[(ihr_ % 5) * ASLOT];                    \
      const int cqa_ = (KS) * 4 + quad;                                       \
      _Pragma("unroll") for (int mt = 0; mt < 8; ++mt) {                      \
        int r_ = mt * 16 + lane15 + (KW);                                     \
        fa##S[mt] = *(const s8v*)&ap_[(r_ * 8 + (cqa_ ^ (r_ & 7))) * 8];      \
      } } }

#define READ_B(S, BUF, KS)                                                    \
  { const unsigned short* bp_ = lB[BUF];                                      \
    const int cqb_ = (KS) * 4 + quad;                                         \
    _Pragma("unroll") for (int nt = 0; nt < 4; ++nt) {                        \
      int n_ = (wn << 6) + nt * 16 + lane15;                                  \
      fb##S[nt] = *(const s8v*)&bp_[(n_ * 8 + (cqb_ ^ (n_ & 7))) * 8];        \
    } }

#define DO_MFMA(S)                                                            \
  if (rowok_) {                                                               \
    _Pragma("unroll") for (int mt = 0; mt < 8; ++mt)                          \
      _Pragma("unroll") for (int nt = 0; nt < 4; ++nt)                        \
        acc[mt][nt] = __builtin_amdgcn_mfma_f32_16x16x32_bf16(                \
            fa##S[mt], fb##S[nt], acc[mt][nt], 0, 0, 0);                      \
  }

__global__ __launch_bounds__(512, 2) void conv_kernel(const __hip_bfloat16* __restrict__ up,
                                                      const __hip_bfloat16* __restrict__ Wr,
                                                      float* __restrict__ out,
                                                      float* __restrict__ gstats) {
  __shared__ __align__(16) unsigned short lA[5 * ASLOT];     //  84480 B
  __shared__ __align__(16) unsigned short lB[4][128 * 64];   //  65536 B
  __shared__ float lsum[128], lssq[128];                     //   1024 B -> 151040 total

  const int tid = threadIdx.x;
  const int lane = tid & 63;
  const int wave = tid >> 6;
  const int wm = wave >> 1;   // output row within 4-row group
  const int wn = wave & 1;    // cout half
  const int lane15 = lane & 15;
  const int quad = lane >> 4;
  const int wb = wave << 6;   // wave chunk base

  const int bid = blockIdx.x;
  const int orig = ((bid & 7) << 5) | (bid >> 3);  // XCD-chunked: each XCD owns one batch image
  const int b = orig >> 5;
  const int oh0 = (orig & 31) << 2;

  const f4v zero4 = {0.f, 0.f, 0.f, 0.f};
  if (tid < 128) { lsum[tid] = 0.f; lssq[tid] = 0.f; }
  // zero kw-halo rows (0,1,130,131 <-> iw -2,-1,128,129) of all 5 slots; never re-staged
  if (tid < 160) {
    int s = tid >> 5, j = tid & 31;
    int rsel = j >> 3;
    int r = (rsel < 2) ? rsel : (128 + rsel);
    *(f4v*)&lA[s * ASLOT + (r * 8 + (j & 7)) * 8] = zero4;
  }

  auto stageA = [&](int slot, const __hip_bfloat16* uprow) {  // rows 2..129 (iw 0..127), 2 ops/wave
#pragma unroll
    for (int t = 0; t < 2; ++t) {
      int pl = t * 512 + wb + lane;  // 0..1023
      int riw = pl >> 3, pc = pl & 7;
      int r = riw + 2;
      int cq = pc ^ (r & 7);
      async_copy16(uprow + riw * 256 + cq * 8, (void*)&lA[slot * ASLOT + (16 + t * 512 + wb) * 8]);
    }
  };
  auto stageB = [&](const __hip_bfloat16* wsrc, int bsel) {  // [128 cout][64 ch], 2 ops/wave
#pragma unroll
    for (int t = 0; t < 2; ++t) {
      int pl = t * 512 + wb + lane;
      int n = pl >> 3, pc = pl & 7;
      int cq = pc ^ (n & 7);
      async_copy16(wsrc + n * 256 + cq * 8, (void*)&lB[bsel][(t * 512 + wb) * 8]);
    }
  };

  f4v acc[8][4];
#pragma unroll
  for (int i = 0; i < 8; ++i)
#pragma unroll
    for (int j = 0; j < 4; ++j) acc[i][j] = zero4;

  s8v fa0[8], fb0[4];  // set 0: holds current ks0 fragments at round entry
  s8v fa1[8], fb1[4];  // set 1: ks1 fragments (read during sub-round A)

  // ---- prologue: prime lA rows oh0-2..oh0+1 (cb=0) + lB pos0 -> buf0, pos1 -> buf1
  for (int rr = 0; rr < 4; ++rr) {
    int ih = oh0 + rr - 2;
    if ((unsigned)ih < 128u)
      stageA(ih % 5, up + (size_t)(b * 128 + ih) * 32768);
  }
  stageB(Wr, 0);
  stageB(Wr + 32768, 1);
  __syncthreads();  // drains prologue DMA + makes halo zeros / lsum init visible (one-time)

  // preload F(0, ks0)
  READ_A(0, 0, 0, 0);
  READ_B(0, 0, 0);

#pragma unroll 1
  for (int t_ = 0; t_ < 100; ++t_) {
    const int cb_ = t_ / 25, pos_ = t_ % 25;
    const int kh_ = pos_ / 5, kw_ = pos_ % 5;
    const int c0_ = cb_ << 6;
    const bool bnd_ = (cb_ != 0 && pos_ == 0);
    // ---- stage phase ----
    if (bnd_) {  // cb boundary: re-prime lA window at new channels (behind prior extra barrier)
      for (int rr_ = 0; rr_ < 4; ++rr_) {
        int ihn_ = oh0 + rr_ - 2;
        if ((unsigned)ihn_ < 128u)
          stageA(ihn_ % 5, up + (size_t)(b * 128 + ihn_) * 32768 + c0_);
      }
    }
    if (t_ <= 97) {  // stage lB two rounds ahead into buf (t+2)%4
      const int tt_ = t_ + 2;
      stageB(Wr + (size_t)(tt_ % 25) * 32768 + ((tt_ / 25) << 6), tt_ & 3);
    }
    const bool exA_ = (kw_ == 2) && (kh_ < 4) && (oh0 + kh_ + 2 < 128);
    if (exA_)  // lA row for kh+1; slot disjoint from rounds t-1..t+1 read sets
      stageA((oh0 + kh_ + 2) % 5, up + (size_t)(b * 128 + oh0 + kh_ + 2) * 32768 + c0_);
    // ---- counted wait (this round's ops stay in flight; <=t-1's have landed) ----
    if (t_ > 97)      { WAITVM(0); }
    else if (bnd_)    { WAITVM(2); }   // drain re-prime (issued first), keep stageB
    else if (exA_)    { WAITVM(4); }   // stageB + stageA
    else              { WAITVM(2); }   // stageB only
    block_barrier();
    // ---- compute: MFMA from preloaded regs while next fragments stream from LDS ----
    const int ih_ = oh0 + wm + kh_ - 2;
    const bool rowok_ = (unsigned)ih_ < 128u;
    __builtin_amdgcn_s_setprio(1);
    if (bnd_) {  // slow path (3x/kernel): ks0 was not prefetchable across the boundary
      READ_A(0, kh_, kw_, 0);
      READ_B(0, t_ & 3, 0);
    }
    // sub-round A: read ks1 -> set1; MFMA ks0 from set0 (no lgkm dependency)
    READ_A(1, kh_, kw_, 1);
    READ_B(1, t_ & 3, 1);
    DO_MFMA(0);
    // sub-round B: read next pos's ks0 -> set0; MFMA ks1 from set1
    if (t_ < 99 && ((t_ + 1) % 25) != 0) {  // skip when t+1 is a cb boundary (or end)
      const int p1_ = (t_ + 1) % 25;
      READ_A(0, p1_ / 5, p1_ % 5, 0);
      READ_B(0, (t_ + 1) & 3, 0);
    }
    DO_MFMA(1);
    __builtin_amdgcn_s_setprio(0);
    if (pos_ == 24 && cb_ < 3) block_barrier();  // all old-channel reads done before re-prime
  }

  // ---- epilogue: direct stores from acc (D: cout=lane&15, ow=mt*16+quad*4+reg) + stats
  const int oh = oh0 + wm;
#pragma unroll
  for (int nt = 0; nt < 4; ++nt) {
    const int n = (wn << 6) + nt * 16 + lane15;
    float* oc = out + ((size_t)(b * 128 + n) * 128 + oh) * 128;
    float s = 0.f, ss = 0.f;
#pragma unroll
    for (int mt = 0; mt < 8; ++mt) {
      f4v v = acc[mt][nt];
      *(f4v*)&oc[mt * 16 + (quad << 2)] = v;
      s += v.x + v.y + v.z + v.w;
      ss += v.x * v.x + v.y * v.y + v.z * v.z + v.w * v.w;
    }
    s += __shfl_xor(s, 16, 64); ss += __shfl_xor(ss, 16, 64);
    s += __shfl_xor(s, 32, 64); ss += __shfl_xor(ss, 32, 64);
    if (quad == 0) { atomicAdd(&lsum[n], s); atomicAdd(&lssq[n], ss); }
  }
  __syncthreads();
  if (tid < 128) {
    atomicAdd(&gstats[tid], lsum[tid]);
    atomicAdd(&gstats[128 + tid], lssq[tid]);
  }
}

// ---------------- Normalize + ReLU in-place, grid-stride ----------------
__global__ __launch_bounds__(256) void norm_kernel(float* __restrict__ out,
                                                   const float* __restrict__ gstats,
                                                   const float* __restrict__ gamma,
                                                   const float* __restrict__ beta) {
  for (int i = blockIdx.x * 256 + threadIdx.x; i < 4194304; i += 2048 * 256) {
    f4v v = ((f4v*)out)[i];
    int c = (i >> 12) & 127;
    float mean = gstats[c] * (1.f / 131072.f);
    float var = gstats[128 + c] * (1.f / 131072.f) - mean * mean;
    float sc = gamma[c] * rsqrtf(var + 1e-5f);
    float bi = beta[c] - mean * sc;
    v.x = fmaxf(fmaf(v.x, sc, bi), 0.f);
    v.y = fmaxf(fmaf(v.y, sc, bi), 0.f);
    v.z = fmaxf(fmaf(v.z, sc, bi), 0.f);
    v.w = fmaxf(fmaf(v.w, sc, bi), 0.f);
    ((f4v*)out)[i] = v;
  }
}

extern "C" void kernel_launch(void* const* d_in, const int* in_sizes, int n_in,
                              void* d_out, int out_size, void* d_ws, size_t ws_size,
                              hipStream_t stream) {
  (void)in_sizes; (void)n_in; (void)out_size; (void)ws_size;
  const float* x = (const float*)d_in[0];
  const float* W = (const float*)d_in[1];
  const float* gamma = (const float*)d_in[2];
  const float* beta = (const float*)d_in[3];
  float* out = (float*)d_out;
  char* ws = (char*)d_ws;
  __hip_bfloat16* up = (__hip_bfloat16*)ws;                       // 67,108,864 B
  __hip_bfloat16* Wr = (__hip_bfloat16*)(ws + 67108864);          // 1,638,400 B
  float* gstats = (float*)(ws + 67108864 + 1638400);              // sum[128], sumsq[128]

  wpack_kernel<<<128, 256, 0, stream>>>(W, Wr, gstats);           // also zeroes gstats
  upsample_kernel<<<512, 256, 0, stream>>>(x, up);
  conv_kernel<<<256, 512, 0, stream>>>(up, Wr, out, gstats);
  norm_kernel<<<2048, 256, 0, stream>>>(out, gstats, gamma, beta);
}

// Round 7
// 332.107 us; speedup vs baseline: 1.0262x; 1.0016x over previous
//
#include <hip/hip_runtime.h>
#include <hip/hip_bf16.h>
#include <stdint.h>

typedef short s8v __attribute__((ext_vector_type(8)));
typedef float f4v __attribute__((ext_vector_type(4)));
typedef float f16v __attribute__((ext_vector_type(16)));

__device__ __forceinline__ void async_copy16(const void* gsrc, void* lds_dst) {
  __builtin_amdgcn_global_load_lds(
      (const __attribute__((address_space(1))) uint32_t*)(uintptr_t)gsrc,
      (__attribute__((address_space(3))) uint32_t*)(uint32_t)(uintptr_t)lds_dst,
      16, 0, 0);
}

#define WAITVM(N) asm volatile("s_waitcnt vmcnt(" #N ")" ::: "memory")
__device__ __forceinline__ void block_barrier() {
  asm volatile("" ::: "memory");
  __builtin_amdgcn_s_barrier();
  asm volatile("" ::: "memory");
}

// ---------------- W pack: [co][ci][kh][kw] fp32 -> [kh*5+kw][co][ci] bf16 ----------------
__global__ __launch_bounds__(256) void wpack_kernel(const float* __restrict__ W,
                                                    __hip_bfloat16* __restrict__ Wr,
                                                    float* __restrict__ gstats) {
  __shared__ __hip_bfloat16 t[256 * 26];  // [ci][pos], pad to 26
  const int co = blockIdx.x;
  const int tid = threadIdx.x;
  if (co == 0) gstats[tid] = 0.f;  // 256 floats: sum[128], ssq[128]
  const float* src = W + co * 6400;
  for (int i = tid; i < 6400; i += 256) {
    int ci = i / 25;
    int pos = i - ci * 25;
    t[ci * 26 + pos] = __float2bfloat16(src[i]);
  }
  __syncthreads();
  for (int pos = 0; pos < 25; ++pos)
    Wr[pos * 32768 + co * 256 + tid] = t[tid * 26 + pos];
}

// ---------------- Upsample: x NCHW fp32 (8,256,64,64) -> up NHWC bf16 (8,128,128,256) ----------------
__global__ __launch_bounds__(256, 2) void upsample_kernel(const float* __restrict__ x,
                                                          __hip_bfloat16* __restrict__ up) {
  __shared__ __hip_bfloat16 lx[10 * 48 * 66];  // [ih 10][iw 48][c 64 + 2 pad]
  const int tid = threadIdx.x;
  const int bx = blockIdx.x;
  const int owb = bx & 1;
  const int ohb = (bx >> 1) & 7;
  const int cb = (bx >> 4) & 3;
  const int b = bx >> 6;
  const int oh0 = ohb * 16, ow0 = owb * 64, c0 = cb * 64;
  const int ih0 = (oh0 >> 1) - 1;                    // may be -1
  const int iw_lo = (ow0 >> 1) - 1;
  const int aligned = (iw_lo < 0 ? 0 : iw_lo) & ~15; // 0 or 16

  for (int i = tid; i < 64 * 10 * 12; i += 256) {    // float4 loads along iw
    int c = i / 120;
    int rem = i - c * 120;
    int r = rem / 12;
    int w4 = (rem - r * 12) * 4;
    int gr = ih0 + r;
    gr = gr < 0 ? 0 : (gr > 63 ? 63 : gr);
    const float4 v = *(const float4*)&x[(((b * 256 + c0 + c) * 64) + gr) * 64 + aligned + w4];
    int base = (r * 48 + w4) * 66 + c;
    lx[base]       = __float2bfloat16(v.x);
    lx[base + 66]  = __float2bfloat16(v.y);
    lx[base + 132] = __float2bfloat16(v.z);
    lx[base + 198] = __float2bfloat16(v.w);
  }
  __syncthreads();

  const int c2 = (tid & 31) * 2;
  const int owq = tid >> 5;  // 0..7
  uint32_t* upu = (uint32_t*)up;
  for (int it = 0; it < 128; ++it) {
    int oh_l = it >> 3;
    int ow_l = (it & 7) * 8 + owq;
    int oh = oh0 + oh_l, ow = ow0 + ow_l;
    int ihA = (oh >> 1) - ((oh & 1) ^ 1);            // first tap row
    float wh = (oh & 1) ? 0.75f : 0.25f;             // its weight
    int iwA = (ow >> 1) - ((ow & 1) ^ 1);
    float wwt = (ow & 1) ? 0.75f : 0.25f;
    int r0 = ihA - ih0;                               // slot content is pre-clamped
    int w0 = (iwA < 0 ? 0 : iwA) - aligned;
    int w1t = iwA + 1; w1t = w1t > 63 ? 63 : w1t;
    int w1 = w1t - aligned;
    uint32_t t00 = *(const uint32_t*)&lx[(r0 * 48 + w0) * 66 + c2];
    uint32_t t01 = *(const uint32_t*)&lx[(r0 * 48 + w1) * 66 + c2];
    uint32_t t10 = *(const uint32_t*)&lx[((r0 + 1) * 48 + w0) * 66 + c2];
    uint32_t t11 = *(const uint32_t*)&lx[((r0 + 1) * 48 + w1) * 66 + c2];
    float wlo = wh * wwt, wlo1 = wh * (1.f - wwt);
    float whi = (1.f - wh) * wwt, whi1 = (1.f - wh) * (1.f - wwt);
    float vlo = wlo * __uint_as_float(t00 << 16) + wlo1 * __uint_as_float(t01 << 16) +
                whi * __uint_as_float(t10 << 16) + whi1 * __uint_as_float(t11 << 16);
    float vhi = wlo * __uint_as_float(t00 & 0xffff0000u) + wlo1 * __uint_as_float(t01 & 0xffff0000u) +
                whi * __uint_as_float(t10 & 0xffff0000u) + whi1 * __uint_as_float(t11 & 0xffff0000u);
    __hip_bfloat16 h0 = __float2bfloat16(vlo);
    __hip_bfloat16 h1 = __float2bfloat16(vhi);
    uint32_t pk = (uint32_t)(*(unsigned short*)&h0) | ((uint32_t)(*(unsigned short*)&h1) << 16);
    upu[((((size_t)(b * 128 + oh) * 128) + ow) * 256 + c0 + c2) >> 1] = pk;
  }
}

// ---------------- Conv: implicit GEMM, M=512 x N=128, MFMA 32x32x16, register-pipelined ----------------
// grid: 256 blocks (1 per CU) = b(8) x ohg(32), 512 threads (8 waves: 4 rows x 2 cout-halves).
// Wave tile 128 ow x 64 cout = 4(mt) x 2(nt) MFMA_32x32 x 4 ksteps of K=16 per round.
// Fragment register pipeline (r6's schedule at HALF the register pressure): enter round with ks0
// fragments loaded; each kstep {read next kstep's 6 frags || 8 MFMAs}; kstep3 reads NEXT round's
// ks0 (legal: its lB buf was staged 2 rounds ago and drained by this round's counted vmcnt).
// A/B layout (32x32x16 bf16): m/n = lane&31, k = (lane>>5)*8 + e  [doubling pattern of the
// verified 16x16x32 mapping]. C/D (m74/m101): col(lane&31)=cout, row=(reg&3)+8*(reg>>2)+4*(lane>>5)=ow.
// lB QUAD-buffered (read t%3.. {t-1,t,t+1} read-set disjoint from write (t+2)%4).
// lA: 5-slot circular row window; stageA at kw==2; cb-boundary re-prime behind extra barrier.
#define ASLOT 8448  // shorts per lA slot (132 rows * 64 ch)

#define READ_A32(DST, KH, KW, KS)                                             \
  { int ihr_ = oh0 + wm + (KH) - 2;                                           \
    if ((unsigned)ihr_ < 128u) {                                              \
      const unsigned short* ap_ = &lA[(ihr_ % 5) * ASLOT];                    \
      const int cqa_ = (KS) * 2 + half;                                       \
      _Pragma("unroll") for (int mt = 0; mt < 4; ++mt) {                      \
        int r_ = mt * 32 + lane31 + (KW);                                     \
        DST[mt] = *(const s8v*)&ap_[(r_ * 8 + (cqa_ ^ (r_ & 7))) * 8];        \
      } } }

#define READ_B32(DST, BUF, KS)                                                \
  { const unsigned short* bp_ = lB[BUF];                                      \
    const int cqb_ = (KS) * 2 + half;                                         \
    _Pragma("unroll") for (int nt = 0; nt < 2; ++nt) {                        \
      int n_ = (wn << 6) + nt * 32 + lane31;                                  \
      DST[nt] = *(const s8v*)&bp_[(n_ * 8 + (cqb_ ^ (n_ & 7))) * 8];          \
    } }

#define MFMA32(ASET, BSET)                                                    \
  if (rowok_) {                                                               \
    _Pragma("unroll") for (int mt = 0; mt < 4; ++mt)                          \
      _Pragma("unroll") for (int nt = 0; nt < 2; ++nt)                        \
        acc[mt][nt] = __builtin_amdgcn_mfma_f32_32x32x16_bf16(                \
            ASET[mt], BSET[nt], acc[mt][nt], 0, 0, 0);                        \
  }

__global__ __launch_bounds__(512, 2) void conv_kernel(const __hip_bfloat16* __restrict__ up,
                                                      const __hip_bfloat16* __restrict__ Wr,
                                                      float* __restrict__ out,
                                                      float* __restrict__ gstats) {
  __shared__ __align__(16) unsigned short lA[5 * ASLOT];     //  84480 B
  __shared__ __align__(16) unsigned short lB[4][128 * 64];   //  65536 B
  __shared__ float lsum[128], lssq[128];                     //   1024 B -> 151040 total

  const int tid = threadIdx.x;
  const int lane = tid & 63;
  const int wave = tid >> 6;
  const int wm = wave >> 1;   // output row within 4-row group
  const int wn = wave & 1;    // cout half
  const int lane31 = lane & 31;
  const int half = lane >> 5;
  const int wb = wave << 6;   // wave chunk base

  const int bid = blockIdx.x;
  const int orig = ((bid & 7) << 5) | (bid >> 3);  // XCD-chunked: each XCD owns one batch image
  const int b = orig >> 5;
  const int oh0 = (orig & 31) << 2;

  const f4v zero4 = {0.f, 0.f, 0.f, 0.f};
  if (tid < 128) { lsum[tid] = 0.f; lssq[tid] = 0.f; }
  // zero kw-halo rows (0,1,130,131 <-> iw -2,-1,128,129) of all 5 slots; never re-staged
  if (tid < 160) {
    int s = tid >> 5, j = tid & 31;
    int rsel = j >> 3;
    int r = (rsel < 2) ? rsel : (128 + rsel);
    *(f4v*)&lA[s * ASLOT + (r * 8 + (j & 7)) * 8] = zero4;
  }

  auto stageA = [&](int slot, const __hip_bfloat16* uprow) {  // rows 2..129 (iw 0..127), 2 ops/wave
#pragma unroll
    for (int t = 0; t < 2; ++t) {
      int pl = t * 512 + wb + lane;  // 0..1023
      int riw = pl >> 3, pc = pl & 7;
      int r = riw + 2;
      int cq = pc ^ (r & 7);
      async_copy16(uprow + riw * 256 + cq * 8, (void*)&lA[slot * ASLOT + (16 + t * 512 + wb) * 8]);
    }
  };
  auto stageB = [&](const __hip_bfloat16* wsrc, int bsel) {  // [128 cout][64 ch], 2 ops/wave
#pragma unroll
    for (int t = 0; t < 2; ++t) {
      int pl = t * 512 + wb + lane;
      int n = pl >> 3, pc = pl & 7;
      int cq = pc ^ (n & 7);
      async_copy16(wsrc + n * 256 + cq * 8, (void*)&lB[bsel][(t * 512 + wb) * 8]);
    }
  };

  f16v acc[4][2];
#pragma unroll
  for (int i = 0; i < 4; ++i)
#pragma unroll
    for (int j = 0; j < 2; ++j)
#pragma unroll
      for (int e = 0; e < 16; ++e) acc[i][j][e] = 0.f;

  s8v a0[4], b0[2];  // even ksteps
  s8v a1[4], b1[2];  // odd ksteps

  // ---- prologue: prime lA rows oh0-2..oh0+1 (cb=0) + lB pos0 -> buf0, pos1 -> buf1
  for (int rr = 0; rr < 4; ++rr) {
    int ih = oh0 + rr - 2;
    if ((unsigned)ih < 128u)
      stageA(ih % 5, up + (size_t)(b * 128 + ih) * 32768);
  }
  stageB(Wr, 0);
  stageB(Wr + 32768, 1);
  __syncthreads();  // drains prologue DMA + makes halo zeros / lsum init visible (one-time)

  // preload round-0 ks0
  READ_A32(a0, 0, 0, 0);
  READ_B32(b0, 0, 0);

#pragma unroll 1
  for (int t_ = 0; t_ < 100; ++t_) {
    const int cb_ = t_ / 25, pos_ = t_ % 25;
    const int kh_ = pos_ / 5, kw_ = pos_ % 5;
    const int c0_ = cb_ << 6;
    const bool bnd_ = (cb_ != 0 && pos_ == 0);
    // ---- stage phase ----
    if (bnd_) {  // cb boundary: re-prime lA window at new channels (behind prior extra barrier)
      for (int rr_ = 0; rr_ < 4; ++rr_) {
        int ihn_ = oh0 + rr_ - 2;
        if ((unsigned)ihn_ < 128u)
          stageA(ihn_ % 5, up + (size_t)(b * 128 + ihn_) * 32768 + c0_);
      }
    }
    if (t_ <= 97) {  // stage lB two rounds ahead into buf (t+2)%4
      const int tt_ = t_ + 2;
      stageB(Wr + (size_t)(tt_ % 25) * 32768 + ((tt_ / 25) << 6), tt_ & 3);
    }
    const bool exA_ = (kw_ == 2) && (kh_ < 4) && (oh0 + kh_ + 2 < 128);
    if (exA_)  // lA row for kh+1; slot disjoint from rounds t-1..t+1 read sets
      stageA((oh0 + kh_ + 2) % 5, up + (size_t)(b * 128 + oh0 + kh_ + 2) * 32768 + c0_);
    // ---- counted wait (this round's ops stay in flight; <=t-1's have landed) ----
    if (t_ > 97)      { WAITVM(0); }
    else if (bnd_)    { WAITVM(2); }   // drain re-prime (issued first), keep stageB
    else if (exA_)    { WAITVM(4); }   // stageB + stageA
    else              { WAITVM(2); }   // stageB only
    block_barrier();
    // ---- compute: 4 ksteps; reads for kstep+1 stream under the 8 MFMAs of kstep ----
    const int ih_ = oh0 + wm + kh_ - 2;
    const bool rowok_ = (unsigned)ih_ < 128u;
    __builtin_amdgcn_s_setprio(1);
    if (bnd_) {  // slow path (3x/kernel): ks0 was not prefetchable across the boundary
      READ_A32(a0, kh_, kw_, 0);
      READ_B32(b0, t_ & 3, 0);
    }
    READ_A32(a1, kh_, kw_, 1);  READ_B32(b1, t_ & 3, 1);
    MFMA32(a0, b0);  // ks0
    READ_A32(a0, kh_, kw_, 2);  READ_B32(b0, t_ & 3, 2);
    MFMA32(a1, b1);  // ks1
    READ_A32(a1, kh_, kw_, 3);  READ_B32(b1, t_ & 3, 3);
    MFMA32(a0, b0);  // ks2
    if (t_ < 99 && ((t_ + 1) % 25) != 0) {  // pre-read next round's ks0 (skip into cb boundary)
      const int p1_ = (t_ + 1) % 25;
      READ_A32(a0, p1_ / 5, p1_ % 5, 0);
      READ_B32(b0, (t_ + 1) & 3, 0);
    }
    MFMA32(a1, b1);  // ks3
    __builtin_amdgcn_s_setprio(0);
    if (pos_ == 24 && cb_ < 3) block_barrier();  // all old-channel reads done before re-prime
  }

  // ---- epilogue: direct stores from acc (D: cout=lane&31, ow=mt*32+8*(reg>>2)+4*half+(reg&3))
  const int oh = oh0 + wm;
#pragma unroll
  for (int nt = 0; nt < 2; ++nt) {
    const int n = (wn << 6) + nt * 32 + lane31;
    float* oc = out + ((size_t)(b * 128 + n) * 128 + oh) * 128;
    float s = 0.f, ss = 0.f;
#pragma unroll
    for (int mt = 0; mt < 4; ++mt) {
      f16v v = acc[mt][nt];
#pragma unroll
      for (int g = 0; g < 4; ++g) {
        f4v p = {v[4 * g], v[4 * g + 1], v[4 * g + 2], v[4 * g + 3]};
        *(f4v*)&oc[mt * 32 + g * 8 + half * 4] = p;
        s += p.x + p.y + p.z + p.w;
        ss += p.x * p.x + p.y * p.y + p.z * p.z + p.w * p.w;
      }
    }
    s += __shfl_xor(s, 32, 64); ss += __shfl_xor(ss, 32, 64);
    if (half == 0) { atomicAdd(&lsum[n], s); atomicAdd(&lssq[n], ss); }
  }
  __syncthreads();
  if (tid < 128) {
    atomicAdd(&gstats[tid], lsum[tid]);
    atomicAdd(&gstats[128 + tid], lssq[tid]);
  }
}

// ---------------- Normalize + ReLU in-place, grid-stride ----------------
__global__ __launch_bounds__(256) void norm_kernel(float* __restrict__ out,
                                                   const float* __restrict__ gstats,
                                                   const float* __restrict__ gamma,
                                                   const float* __restrict__ beta) {
  for (int i = blockIdx.x * 256 + threadIdx.x; i < 4194304; i += 2048 * 256) {
    f4v v = ((f4v*)out)[i];
    int c = (i >> 12) & 127;
    float mean = gstats[c] * (1.f / 131072.f);
    float var = gstats[128 + c] * (1.f / 131072.f) - mean * mean;
    float sc = gamma[c] * rsqrtf(var + 1e-5f);
    float bi = beta[c] - mean * sc;
    v.x = fmaxf(fmaf(v.x, sc, bi), 0.f);
    v.y = fmaxf(fmaf(v.y, sc, bi), 0.f);
    v.z = fmaxf(fmaf(v.z, sc, bi), 0.f);
    v.w = fmaxf(fmaf(v.w, sc, bi), 0.f);
    ((f4v*)out)[i] = v;
  }
}

extern "C" void kernel_launch(void* const* d_in, const int* in_sizes, int n_in,
                              void* d_out, int out_size, void* d_ws, size_t ws_size,
                              hipStream_t stream) {
  (void)in_sizes; (void)n_in; (void)out_size; (void)ws_size;
  const float* x = (const float*)d_in[0];
  const float* W = (const float*)d_in[1];
  const float* gamma = (const float*)d_in[2];
  const float* beta = (const float*)d_in[3];
  float* out = (float*)d_out;
  char* ws = (char*)d_ws;
  __hip_bfloat16* up = (__hip_bfloat16*)ws;                       // 67,108,864 B
  __hip_bfloat16* Wr = (__hip_bfloat16*)(ws + 67108864);          // 1,638,400 B
  float* gstats = (float*)(ws + 67108864 + 1638400);              // sum[128], sumsq[128]

  wpack_kernel<<<128, 256, 0, stream>>>(W, Wr, gstats);           // also zeroes gstats
  upsample_kernel<<<512, 256, 0, stream>>>(x, up);
  conv_kernel<<<256, 512, 0, stream>>>(up, Wr, out, gstats);
  norm_kernel<<<2048, 256, 0, stream>>>(out, gstats, gamma, beta);
}